// Round 12
// baseline (263.209 us; speedup 1.0000x reference)
//
#include <hip/hip_runtime.h>
#include <hip/hip_bf16.h>

#define B_ 32
#define D_ 256
#define N_ 16384
#define F_ 256
#define K_ 32

#define NSPLIT 32
#define NSLICE (N_ / NSPLIT)   // 512

#define L2E 1.4426950408889634f

typedef __attribute__((ext_vector_type(8))) short bf16x8;
typedef __attribute__((ext_vector_type(4))) float f32x4;

__device__ __forceinline__ unsigned short f2bf(float x) {
    unsigned int u = __float_as_uint(x);
    u = (u + 0x7FFFu + ((u >> 16) & 1u)) >> 16;
    return (unsigned short)u;
}

// RNE pack of two f32 -> two bf16 in one dword (x in low, y in high)
__device__ __forceinline__ unsigned int pack_bf16(float x, float y) {
    unsigned int ux = __float_as_uint(x), uy = __float_as_uint(y);
    ux = (ux + 0x7FFFu + ((ux >> 16) & 1u)) >> 16;
    uy = (uy + 0x7FFFu + ((uy >> 16) & 1u)) & 0xFFFF0000u;
    return ux | uy;
}

// pairwise tree sum of 16 (short dependency chains; fp add is not reassociable by compiler)
__device__ __forceinline__ float tree16(const float* a) {
    float t0 = a[0] + a[1],  t1 = a[2] + a[3],  t2 = a[4] + a[5],  t3 = a[6] + a[7];
    float t4 = a[8] + a[9],  t5 = a[10] + a[11], t6 = a[12] + a[13], t7 = a[14] + a[15];
    float u0 = t0 + t1, u1 = t2 + t3, u2 = t4 + t5, u3 = t6 + t7;
    return (u0 + u1) + (u2 + u3);
}

// ---------------- Kernel A: sims[b][n] = -(sum_d q[b][d]*keys[b][d][n]) / 16 ----------------
// In-kernel 2-way d-split: 1024 blocks (4/CU, 16 waves/CU), tile = 512 n.
// half = t>>7 sums d in [half*128, half*128+128); one LDS combine per block.
__global__ __launch_bounds__(256) void sims_kernel(
    const float* __restrict__ q, const float* __restrict__ keys, float* __restrict__ sims)
{
    const int nt = N_ / 512;                  // 32 n-tiles per batch
    int b = blockIdx.x / nt;
    int tile = blockIdx.x % nt;
    int half = threadIdx.x >> 7;              // 0 or 1
    int tl = threadIdx.x & 127;
    int n0 = tile * 512 + tl * 4;

    __shared__ float qs[D_];
    __shared__ float partial[128][4];

    qs[threadIdx.x] = q[b * D_ + threadIdx.x];   // blockDim == D_ == 256
    __syncthreads();

    const float* kb = keys + (size_t)b * D_ * N_ + (size_t)(half * 128) * N_ + n0;
    const float* qh = qs + half * 128;
    float ax = 0.f, ay = 0.f, az = 0.f, aw = 0.f;
    #pragma unroll 8
    for (int d = 0; d < 128; ++d) {
        float4 kv = *reinterpret_cast<const float4*>(kb + (size_t)d * N_);
        float qd = qh[d];
        ax = fmaf(qd, kv.x, ax); ay = fmaf(qd, kv.y, ay);
        az = fmaf(qd, kv.z, az); aw = fmaf(qd, kv.w, aw);
    }
    if (half == 1) {
        partial[tl][0] = ax; partial[tl][1] = ay;
        partial[tl][2] = az; partial[tl][3] = aw;
    }
    __syncthreads();
    if (half == 0) {
        const float sc = -0.0625f;   // -1/sqrt(256)
        float4 o = make_float4((ax + partial[tl][0]) * sc, (ay + partial[tl][1]) * sc,
                               (az + partial[tl][2]) * sc, (aw + partial[tl][3]) * sc);
        *reinterpret_cast<float4*>(sims + b * N_ + n0) = o;
    }
}

// ---------------- block reductions for 512 threads = 8 waves ----------------
__device__ __forceinline__ float blk_max8(float v, volatile float* red) {
    #pragma unroll
    for (int off = 32; off > 0; off >>= 1) v = fmaxf(v, __shfl_xor(v, off));
    if ((threadIdx.x & 63) == 0) red[threadIdx.x >> 6] = v;
    __syncthreads();
    if (threadIdx.x < 64) {
        float w = (threadIdx.x < 8) ? red[threadIdx.x] : -3.0e38f;
        #pragma unroll
        for (int off = 4; off > 0; off >>= 1) w = fmaxf(w, __shfl_xor(w, off));
        if (threadIdx.x == 0) red[16] = w;
    }
    __syncthreads();
    return red[16];
}
__device__ __forceinline__ float blk_sum8(float v, volatile float* red) {
    #pragma unroll
    for (int off = 32; off > 0; off >>= 1) v += __shfl_xor(v, off);
    if ((threadIdx.x & 63) == 0) red[threadIdx.x >> 6] = v;
    __syncthreads();
    if (threadIdx.x < 64) {
        float w = (threadIdx.x < 8) ? red[threadIdx.x] : 0.0f;
        #pragma unroll
        for (int off = 4; off > 0; off >>= 1) w += __shfl_xor(w, off);
        if (threadIdx.x == 0) red[16] = w;
    }
    __syncthreads();
    return red[16];
}

// ---------------- Kernel B: zeta — w0[b][n] = exp(2*alpha0[n]) and izeta[b][k] = 1/Z_k ------
// 512 threads x 32 n/thread: 8-wave barriers, 5-shfl wave reduce (2 partials/wave ->
// 16 partials), tree-structured local sums. K-loop: ONE barrier per iteration (ping-pong).
__global__ __launch_bounds__(512) void zeta_kernel(
    const float* __restrict__ sims, float* __restrict__ w0, float* __restrict__ izeta)
{
    int b = blockIdx.x, t = threadIdx.x;
    __shared__ float red1[17];
    __shared__ float redA[16];
    __shared__ float redB[16];

    // thread t owns 32 contiguous n: [32t, 32t+32)
    const float* sb = sims + (size_t)b * N_ + t * 32;
    float a[32];
    #pragma unroll
    for (int j = 0; j < 32; j += 4) {
        float4 v = *reinterpret_cast<const float4*>(sb + j);
        a[j] = v.x; a[j + 1] = v.y; a[j + 2] = v.z; a[j + 3] = v.w;
    }
    float m0 = -3.0e38f;
    #pragma unroll
    for (int j = 0; j < 32; ++j) m0 = fmaxf(m0, a[j]);
    m0 = blk_max8(m0, red1);

    float zs = 0.f;
    #pragma unroll
    for (int j = 0; j < 32; ++j) {
        a[j] = __builtin_amdgcn_exp2f((a[j] - m0) * L2E);
        zs += a[j];
    }
    float Z = blk_sum8(zs, red1);
    float c2 = 2.0f * L2E / Z;     // alpha0 = a/Z; w = exp2(c2 * a)
    #pragma unroll
    for (int j = 0; j < 32; ++j) a[j] = __builtin_amdgcn_exp2f(a[j] * c2);

    // store w0 (f32, coalesced)
    float* wp = w0 + (size_t)b * N_ + t * 32;
    #pragma unroll
    for (int j = 0; j < 32; j += 4)
        *reinterpret_cast<float4*>(wp + j) = make_float4(a[j], a[j+1], a[j+2], a[j+3]);
    __syncthreads();   // red1 done before ping-pong reuse begins

    for (int k = 0; k < K_; ++k) {
        float zz = tree16(a) + tree16(a + 16);
        #pragma unroll
        for (int off = 16; off > 0; off >>= 1) zz += __shfl_xor(zz, off);  // within 32-lane halves
        float* buf = (k & 1) ? redB : redA;
        if ((t & 31) == 0) buf[t >> 5] = zz;   // 2 partials/wave -> 16
        __syncthreads();
        float4 p0 = *reinterpret_cast<float4*>(&buf[0]);
        float4 p1 = *reinterpret_cast<float4*>(&buf[4]);
        float4 p2 = *reinterpret_cast<float4*>(&buf[8]);
        float4 p3 = *reinterpret_cast<float4*>(&buf[12]);
        float Zk = ((p0.x + p0.y) + (p0.z + p0.w)) + ((p1.x + p1.y) + (p1.z + p1.w))
                 + ((p2.x + p2.y) + (p2.z + p2.w)) + ((p3.x + p3.y) + (p3.z + p3.w));
        float izk = 1.0f / Zk;
        if (t == 0) izeta[b * K_ + k] = izk;
        #pragma unroll
        for (int j = 0; j < 32; ++j) {
            float u = 1.0f - a[j] * izk;
            a[j] *= u * u;
        }
    }
}

// ---------------- Kernel C: MFMA PV with in-LDS omega regeneration -------------------------
// part[b][ns][k][f] = sum_{n in slice} om[k][n]*v[f][n]
// Phase 1: regenerate omega tile [32][512] bf16 into LDS from w0 + izeta (XOR-swizzled).
// Phase 2: C = A*B^T via mfma_16x16x32_bf16; A from LDS, B = values f32->bf16 in-register.
// nb-loop unroll 2: batches 2 iterations' loads (256B/row contiguity, 2x outstanding).
__global__ __launch_bounds__(256, 4) void pv_kernel(
    const float* __restrict__ values, const float* __restrict__ w0,
    const float* __restrict__ izeta, float* __restrict__ part)
{
    int ns = blockIdx.x % NSPLIT;
    int b  = blockIdx.x / NSPLIT;
    int t = threadIdx.x;

    __shared__ unsigned char om_lds[K_ * NSLICE * 2];   // bf16 [32][512], 32 KB, swizzled

    int n0 = ns * NSLICE;

    // ---- phase 1: omega tile (thread t owns n = n0+2t, n0+2t+1) ----
    {
        float2 u2 = *reinterpret_cast<const float2*>(w0 + (size_t)b * N_ + n0 + t * 2);
        float u0 = u2.x, u1 = u2.y;
        const float* zb = izeta + b * K_;
        int colbyte = t * 4;                      // 2 bf16 = 4 bytes
        #pragma unroll 8
        for (int k = 0; k < K_; ++k) {
            float izk = zb[k];                    // uniform scalar load
            float om0 = u0 * izk, om1 = u1 * izk;
            int addr = (k * 1024 + colbyte) ^ ((k & 7) << 4);
            *reinterpret_cast<unsigned int*>(&om_lds[addr]) = pack_bf16(om0, om1);
            float a0 = 1.f - om0, a1 = 1.f - om1;
            u0 *= a0 * a0; u1 *= a1 * a1;
        }
    }
    __syncthreads();

    // ---- phase 2: MFMA ----
    int wv = t >> 6;            // wave 0..3
    int l  = t & 63;
    int lr = l & 15;            // row within 16-tile (k row for A, f row for B)
    int lq = l >> 4;            // 0..3 -> contraction sub-offset *8
    int fbase = wv * 64;

    const float* vb = values + (size_t)b * F_ * N_;

    f32x4 acc[4][2];
    #pragma unroll
    for (int ti = 0; ti < 4; ++ti)
        #pragma unroll
        for (int kt = 0; kt < 2; ++kt)
            acc[ti][kt] = (f32x4){0.f, 0.f, 0.f, 0.f};

    int xr = (lr & 7) << 4;     // (lr+16)&7 == lr&7

    #pragma unroll 2
    for (int nb = 0; nb < NSLICE; nb += 32) {
        int cb = (nb + lq * 8) * 2;               // byte col in row
        bf16x8 a0 = *reinterpret_cast<const bf16x8*>(&om_lds[(lr * 1024 + cb) ^ xr]);
        bf16x8 a1 = *reinterpret_cast<const bf16x8*>(&om_lds[((lr + 16) * 1024 + cb) ^ xr]);
        #pragma unroll
        for (int ti = 0; ti < 4; ++ti) {
            const float* vp = vb + (size_t)(fbase + ti * 16 + lr) * N_ + n0 + nb + lq * 8;
            float4 x0 = *reinterpret_cast<const float4*>(vp);
            float4 x1 = *reinterpret_cast<const float4*>(vp + 4);
            union { unsigned short s[8]; bf16x8 v; } bv;
            bv.s[0] = f2bf(x0.x); bv.s[1] = f2bf(x0.y);
            bv.s[2] = f2bf(x0.z); bv.s[3] = f2bf(x0.w);
            bv.s[4] = f2bf(x1.x); bv.s[5] = f2bf(x1.y);
            bv.s[6] = f2bf(x1.z); bv.s[7] = f2bf(x1.w);
            acc[ti][0] = __builtin_amdgcn_mfma_f32_16x16x32_bf16(a0, bv.v, acc[ti][0], 0, 0, 0);
            acc[ti][1] = __builtin_amdgcn_mfma_f32_16x16x32_bf16(a1, bv.v, acc[ti][1], 0, 0, 0);
        }
    }

    // write partials: part[b][ns][k][f];  D layout: col(f)=lane&15, row(k)=(lane>>4)*4+reg
    float* pb = part + ((size_t)(b * NSPLIT + ns) * K_) * F_;
    #pragma unroll
    for (int ti = 0; ti < 4; ++ti) {
        int f = fbase + ti * 16 + lr;
        #pragma unroll
        for (int kt = 0; kt < 2; ++kt) {
            #pragma unroll
            for (int r = 0; r < 4; ++r) {
                int k = kt * 16 + lq * 4 + r;
                pb[(size_t)k * F_ + f] = acc[ti][kt][r];
            }
        }
    }
}

// ---------------- Kernel D: reduce partials over NSPLIT ----------------
__global__ __launch_bounds__(256) void reduce_kernel(
    const float* __restrict__ part, float* __restrict__ out)
{
    int idx = (blockIdx.x * 256 + threadIdx.x) * 4;   // over B*K*F = 262144
    int f = idx % F_;
    int bk = idx / F_;          // b*K + k
    int k = bk % K_;
    int b = bk / K_;
    const float* p = part + (((size_t)b * NSPLIT) * K_ + k) * F_ + f;
    float4 s = make_float4(0.f, 0.f, 0.f, 0.f);
    #pragma unroll 4
    for (int ns = 0; ns < NSPLIT; ++ns) {
        float4 v = *reinterpret_cast<const float4*>(p + (size_t)ns * K_ * F_);
        s.x += v.x; s.y += v.y; s.z += v.z; s.w += v.w;
    }
    *reinterpret_cast<float4*>(out + idx) = s;
}

// ---------------- launch ----------------
extern "C" void kernel_launch(void* const* d_in, const int* in_sizes, int n_in,
                              void* d_out, int out_size, void* d_ws, size_t ws_size,
                              hipStream_t stream)
{
    const float* q      = (const float*)d_in[0];
    const float* keys   = (const float*)d_in[1];
    const float* values = (const float*)d_in[2];
    float* out = (float*)d_out;

    char* ws = (char*)d_ws;
    float* sims  = (float*)ws;                                   // B*N*4           = 2 MB
    float* w0    = (float*)(ws + (size_t)B_ * N_ * 4);           // B*N*4           = 2 MB
    float* izeta = (float*)(ws + (size_t)2 * B_ * N_ * 4);       // B*K*4           = 4 KB
    float* part  = (float*)(ws + (size_t)2 * B_ * N_ * 4 + 4096);// B*NSPLIT*K*F*4  = 32 MB

    sims_kernel  <<<B_ * (N_ / 512), 256, 0, stream>>>(q, keys, sims);
    zeta_kernel  <<<B_, 512, 0, stream>>>(sims, w0, izeta);
    pv_kernel    <<<B_ * NSPLIT, 256, 0, stream>>>(values, w0, izeta, part);
    reduce_kernel<<<(B_ * K_ * F_) / 1024, 256, 0, stream>>>(part, out);
}

// Round 13
// 249.335 us; speedup vs baseline: 1.0556x; 1.0556x over previous
//
#include <hip/hip_runtime.h>
#include <hip/hip_bf16.h>

#define B_ 32
#define D_ 256
#define N_ 16384
#define F_ 256
#define K_ 32

#define NSPLIT 32
#define NSLICE (N_ / NSPLIT)   // 512

#define L2E 1.4426950408889634f

typedef __attribute__((ext_vector_type(8))) short bf16x8;
typedef __attribute__((ext_vector_type(4))) float f32x4;

__device__ __forceinline__ unsigned short f2bf(float x) {
    unsigned int u = __float_as_uint(x);
    u = (u + 0x7FFFu + ((u >> 16) & 1u)) >> 16;
    return (unsigned short)u;
}

// RNE pack of two f32 -> two bf16 in one dword (x in low, y in high)
__device__ __forceinline__ unsigned int pack_bf16(float x, float y) {
    unsigned int ux = __float_as_uint(x), uy = __float_as_uint(y);
    ux = (ux + 0x7FFFu + ((ux >> 16) & 1u)) >> 16;
    uy = (uy + 0x7FFFu + ((uy >> 16) & 1u)) & 0xFFFF0000u;
    return ux | uy;
}

// pairwise tree sum of 16 (short dependency chains; fp add is not reassociable by compiler)
__device__ __forceinline__ float tree16(const float* a) {
    float t0 = a[0] + a[1],  t1 = a[2] + a[3],  t2 = a[4] + a[5],  t3 = a[6] + a[7];
    float t4 = a[8] + a[9],  t5 = a[10] + a[11], t6 = a[12] + a[13], t7 = a[14] + a[15];
    float u0 = t0 + t1, u1 = t2 + t3, u2 = t4 + t5, u3 = t6 + t7;
    return (u0 + u1) + (u2 + u3);
}

// ---------------- Kernel A: sims[b][n] = -(sum_d q[b][d]*keys[b][d][n]) / 16 ----------------
__global__ __launch_bounds__(256) void sims_kernel(
    const float* __restrict__ q, const float* __restrict__ keys, float* __restrict__ sims)
{
    const int nt = N_ / 1024;                 // 16 n-tiles per batch
    int b = blockIdx.x / nt;
    int tile = blockIdx.x % nt;
    int n0 = tile * 1024 + threadIdx.x * 4;

    __shared__ float qs[D_];
    qs[threadIdx.x] = q[b * D_ + threadIdx.x];   // blockDim == D_ == 256
    __syncthreads();

    const float* kb = keys + (size_t)b * D_ * N_ + n0;
    float ax = 0.f, ay = 0.f, az = 0.f, aw = 0.f;
    #pragma unroll 8
    for (int d = 0; d < D_; ++d) {
        float4 kv = *reinterpret_cast<const float4*>(kb + (size_t)d * N_);
        float qd = qs[d];
        ax = fmaf(qd, kv.x, ax); ay = fmaf(qd, kv.y, ay);
        az = fmaf(qd, kv.z, az); aw = fmaf(qd, kv.w, aw);
    }
    const float sc = -0.0625f;   // -1/sqrt(256)
    float4 o = make_float4(ax * sc, ay * sc, az * sc, aw * sc);
    *reinterpret_cast<float4*>(sims + b * N_ + n0) = o;
}

// ---------------- block reductions for 512 threads = 8 waves ----------------
__device__ __forceinline__ float blk_max8(float v, volatile float* red) {
    #pragma unroll
    for (int off = 32; off > 0; off >>= 1) v = fmaxf(v, __shfl_xor(v, off));
    if ((threadIdx.x & 63) == 0) red[threadIdx.x >> 6] = v;
    __syncthreads();
    if (threadIdx.x < 64) {
        float w = (threadIdx.x < 8) ? red[threadIdx.x] : -3.0e38f;
        #pragma unroll
        for (int off = 4; off > 0; off >>= 1) w = fmaxf(w, __shfl_xor(w, off));
        if (threadIdx.x == 0) red[16] = w;
    }
    __syncthreads();
    return red[16];
}
__device__ __forceinline__ float blk_sum8(float v, volatile float* red) {
    #pragma unroll
    for (int off = 32; off > 0; off >>= 1) v += __shfl_xor(v, off);
    if ((threadIdx.x & 63) == 0) red[threadIdx.x >> 6] = v;
    __syncthreads();
    if (threadIdx.x < 64) {
        float w = (threadIdx.x < 8) ? red[threadIdx.x] : 0.0f;
        #pragma unroll
        for (int off = 4; off > 0; off >>= 1) w += __shfl_xor(w, off);
        if (threadIdx.x == 0) red[16] = w;
    }
    __syncthreads();
    return red[16];
}

// ---------------- Kernel B: zeta — w0[b][n] = exp(2*alpha0[n]) and izeta[b][k] = 1/Z_k ------
// 512 threads x 32 n/thread: 8-wave barriers, 5-shfl wave reduce (2 partials/wave ->
// 16 partials), tree-structured local sums. K-loop: ONE barrier per iteration (ping-pong).
__global__ __launch_bounds__(512) void zeta_kernel(
    const float* __restrict__ sims, float* __restrict__ w0, float* __restrict__ izeta)
{
    int b = blockIdx.x, t = threadIdx.x;
    __shared__ float red1[17];
    __shared__ float redA[16];
    __shared__ float redB[16];

    // thread t owns 32 contiguous n: [32t, 32t+32)
    const float* sb = sims + (size_t)b * N_ + t * 32;
    float a[32];
    #pragma unroll
    for (int j = 0; j < 32; j += 4) {
        float4 v = *reinterpret_cast<const float4*>(sb + j);
        a[j] = v.x; a[j + 1] = v.y; a[j + 2] = v.z; a[j + 3] = v.w;
    }
    float m0 = -3.0e38f;
    #pragma unroll
    for (int j = 0; j < 32; ++j) m0 = fmaxf(m0, a[j]);
    m0 = blk_max8(m0, red1);

    float zs = 0.f;
    #pragma unroll
    for (int j = 0; j < 32; ++j) {
        a[j] = __builtin_amdgcn_exp2f((a[j] - m0) * L2E);
        zs += a[j];
    }
    float Z = blk_sum8(zs, red1);
    float c2 = 2.0f * L2E / Z;     // alpha0 = a/Z; w = exp2(c2 * a)
    #pragma unroll
    for (int j = 0; j < 32; ++j) a[j] = __builtin_amdgcn_exp2f(a[j] * c2);

    // store w0 (f32, coalesced)
    float* wp = w0 + (size_t)b * N_ + t * 32;
    #pragma unroll
    for (int j = 0; j < 32; j += 4)
        *reinterpret_cast<float4*>(wp + j) = make_float4(a[j], a[j+1], a[j+2], a[j+3]);
    __syncthreads();   // red1 done before ping-pong reuse begins

    for (int k = 0; k < K_; ++k) {
        float zz = tree16(a) + tree16(a + 16);
        #pragma unroll
        for (int off = 16; off > 0; off >>= 1) zz += __shfl_xor(zz, off);  // within 32-lane halves
        float* buf = (k & 1) ? redB : redA;
        if ((t & 31) == 0) buf[t >> 5] = zz;   // 2 partials/wave -> 16
        __syncthreads();
        float4 p0 = *reinterpret_cast<float4*>(&buf[0]);
        float4 p1 = *reinterpret_cast<float4*>(&buf[4]);
        float4 p2 = *reinterpret_cast<float4*>(&buf[8]);
        float4 p3 = *reinterpret_cast<float4*>(&buf[12]);
        float Zk = ((p0.x + p0.y) + (p0.z + p0.w)) + ((p1.x + p1.y) + (p1.z + p1.w))
                 + ((p2.x + p2.y) + (p2.z + p2.w)) + ((p3.x + p3.y) + (p3.z + p3.w));
        float izk = 1.0f / Zk;
        if (t == 0) izeta[b * K_ + k] = izk;
        #pragma unroll
        for (int j = 0; j < 32; ++j) {
            float u = 1.0f - a[j] * izk;
            a[j] *= u * u;
        }
    }
}

// ---------------- Kernel C: MFMA PV with in-LDS omega regeneration -------------------------
// part[b][ns][k][f] = sum_{n in slice} om[k][n]*v[f][n]
// Phase 1: regenerate omega tile [32][512] bf16 into LDS from w0 + izeta (XOR-swizzled).
// Phase 2: C = A*B^T via mfma_16x16x32_bf16; A from LDS, B = values f32->bf16 in-register.
// nb-loop unroll 2: batches 2 iterations' loads (256B/row contiguity, 2x outstanding).
__global__ __launch_bounds__(256, 4) void pv_kernel(
    const float* __restrict__ values, const float* __restrict__ w0,
    const float* __restrict__ izeta, float* __restrict__ part)
{
    int ns = blockIdx.x % NSPLIT;
    int b  = blockIdx.x / NSPLIT;
    int t = threadIdx.x;

    __shared__ unsigned char om_lds[K_ * NSLICE * 2];   // bf16 [32][512], 32 KB, swizzled

    int n0 = ns * NSLICE;

    // ---- phase 1: omega tile (thread t owns n = n0+2t, n0+2t+1) ----
    {
        float2 u2 = *reinterpret_cast<const float2*>(w0 + (size_t)b * N_ + n0 + t * 2);
        float u0 = u2.x, u1 = u2.y;
        const float* zb = izeta + b * K_;
        int colbyte = t * 4;                      // 2 bf16 = 4 bytes
        #pragma unroll 8
        for (int k = 0; k < K_; ++k) {
            float izk = zb[k];                    // uniform scalar load
            float om0 = u0 * izk, om1 = u1 * izk;
            int addr = (k * 1024 + colbyte) ^ ((k & 7) << 4);
            *reinterpret_cast<unsigned int*>(&om_lds[addr]) = pack_bf16(om0, om1);
            float a0 = 1.f - om0, a1 = 1.f - om1;
            u0 *= a0 * a0; u1 *= a1 * a1;
        }
    }
    __syncthreads();

    // ---- phase 2: MFMA ----
    int wv = t >> 6;            // wave 0..3
    int l  = t & 63;
    int lr = l & 15;            // row within 16-tile (k row for A, f row for B)
    int lq = l >> 4;            // 0..3 -> contraction sub-offset *8
    int fbase = wv * 64;

    const float* vb = values + (size_t)b * F_ * N_;

    f32x4 acc[4][2];
    #pragma unroll
    for (int ti = 0; ti < 4; ++ti)
        #pragma unroll
        for (int kt = 0; kt < 2; ++kt)
            acc[ti][kt] = (f32x4){0.f, 0.f, 0.f, 0.f};

    int xr = (lr & 7) << 4;     // (lr+16)&7 == lr&7

    #pragma unroll 2
    for (int nb = 0; nb < NSLICE; nb += 32) {
        int cb = (nb + lq * 8) * 2;               // byte col in row
        bf16x8 a0 = *reinterpret_cast<const bf16x8*>(&om_lds[(lr * 1024 + cb) ^ xr]);
        bf16x8 a1 = *reinterpret_cast<const bf16x8*>(&om_lds[((lr + 16) * 1024 + cb) ^ xr]);
        #pragma unroll
        for (int ti = 0; ti < 4; ++ti) {
            const float* vp = vb + (size_t)(fbase + ti * 16 + lr) * N_ + n0 + nb + lq * 8;
            float4 x0 = *reinterpret_cast<const float4*>(vp);
            float4 x1 = *reinterpret_cast<const float4*>(vp + 4);
            union { unsigned short s[8]; bf16x8 v; } bv;
            bv.s[0] = f2bf(x0.x); bv.s[1] = f2bf(x0.y);
            bv.s[2] = f2bf(x0.z); bv.s[3] = f2bf(x0.w);
            bv.s[4] = f2bf(x1.x); bv.s[5] = f2bf(x1.y);
            bv.s[6] = f2bf(x1.z); bv.s[7] = f2bf(x1.w);
            acc[ti][0] = __builtin_amdgcn_mfma_f32_16x16x32_bf16(a0, bv.v, acc[ti][0], 0, 0, 0);
            acc[ti][1] = __builtin_amdgcn_mfma_f32_16x16x32_bf16(a1, bv.v, acc[ti][1], 0, 0, 0);
        }
    }

    // write partials: part[b][ns][k][f];  D layout: col(f)=lane&15, row(k)=(lane>>4)*4+reg
    float* pb = part + ((size_t)(b * NSPLIT + ns) * K_) * F_;
    #pragma unroll
    for (int ti = 0; ti < 4; ++ti) {
        int f = fbase + ti * 16 + lr;
        #pragma unroll
        for (int kt = 0; kt < 2; ++kt) {
            #pragma unroll
            for (int r = 0; r < 4; ++r) {
                int k = kt * 16 + lq * 4 + r;
                pb[(size_t)k * F_ + f] = acc[ti][kt][r];
            }
        }
    }
}

// ---------------- Kernel D: reduce partials over NSPLIT ----------------
__global__ __launch_bounds__(256) void reduce_kernel(
    const float* __restrict__ part, float* __restrict__ out)
{
    int idx = (blockIdx.x * 256 + threadIdx.x) * 4;   // over B*K*F = 262144
    int f = idx % F_;
    int bk = idx / F_;          // b*K + k
    int k = bk % K_;
    int b = bk / K_;
    const float* p = part + (((size_t)b * NSPLIT) * K_ + k) * F_ + f;
    float4 s = make_float4(0.f, 0.f, 0.f, 0.f);
    #pragma unroll 4
    for (int ns = 0; ns < NSPLIT; ++ns) {
        float4 v = *reinterpret_cast<const float4*>(p + (size_t)ns * K_ * F_);
        s.x += v.x; s.y += v.y; s.z += v.z; s.w += v.w;
    }
    *reinterpret_cast<float4*>(out + idx) = s;
}

// ---------------- launch ----------------
extern "C" void kernel_launch(void* const* d_in, const int* in_sizes, int n_in,
                              void* d_out, int out_size, void* d_ws, size_t ws_size,
                              hipStream_t stream)
{
    const float* q      = (const float*)d_in[0];
    const float* keys   = (const float*)d_in[1];
    const float* values = (const float*)d_in[2];
    float* out = (float*)d_out;

    char* ws = (char*)d_ws;
    float* sims  = (float*)ws;                                   // B*N*4           = 2 MB
    float* w0    = (float*)(ws + (size_t)B_ * N_ * 4);           // B*N*4           = 2 MB
    float* izeta = (float*)(ws + (size_t)2 * B_ * N_ * 4);       // B*K*4           = 4 KB
    float* part  = (float*)(ws + (size_t)2 * B_ * N_ * 4 + 4096);// B*NSPLIT*K*F*4  = 32 MB

    sims_kernel  <<<B_ * (N_ / 1024), 256, 0, stream>>>(q, keys, sims);
    zeta_kernel  <<<B_, 512, 0, stream>>>(sims, w0, izeta);
    pv_kernel    <<<B_ * NSPLIT, 256, 0, stream>>>(values, w0, izeta, part);
    reduce_kernel<<<(B_ * K_ * F_) / 1024, 256, 0, stream>>>(part, out);
}